// Round 4
// baseline (209.753 us; speedup 1.0000x reference)
//
#include <hip/hip_runtime.h>

typedef unsigned short u16;
typedef unsigned int u32;
typedef float f4 __attribute__((ext_vector_type(4)));
typedef __bf16 b8 __attribute__((ext_vector_type(8)));
typedef _Float16 h4 __attribute__((ext_vector_type(4)));
typedef _Float16 h8 __attribute__((ext_vector_type(8)));
typedef __fp16 hp2 __attribute__((ext_vector_type(2)));

#if __has_builtin(__builtin_amdgcn_exp2f)
#define EXP2(x) __builtin_amdgcn_exp2f(x)
#else
#define EXP2(x) exp2f(x)
#endif

__device__ __forceinline__ u16 f2bf(float f) {
  unsigned u = __float_as_uint(f);
  u += 0x7fffu + ((u >> 16) & 1u);
  return (u16)(u >> 16);
}
__device__ __forceinline__ float bf2f(u16 h) {
  return __uint_as_float(((unsigned)h) << 16);
}

// ------- fused input conversion: x fp32->bf16 + both weights fp32->bf16 transposed -------
__global__ void k_convert_all(const float* __restrict__ x,
                              const float* __restrict__ w_qkv,
                              const float* __restrict__ w_proj,
                              u16* __restrict__ xb, u16* __restrict__ wqkT,
                              u16* __restrict__ wpjT) {
  __shared__ u16 t[64][65];
  int bid = blockIdx.x;
  if (bid < 2048) {  // x convert, same layout
    int i = (bid * 256 + threadIdx.x) * 8;
    float4 a = *(const float4*)(x + i);
    float4 b = *(const float4*)(x + i + 4);
    union { u16 h[8]; uint4 v; } r;
    r.h[0] = f2bf(a.x); r.h[1] = f2bf(a.y); r.h[2] = f2bf(a.z); r.h[3] = f2bf(a.w);
    r.h[4] = f2bf(b.x); r.h[5] = f2bf(b.y); r.h[6] = f2bf(b.z); r.h[7] = f2bf(b.w);
    *(uint4*)(xb + i) = r.v;
    return;
  }
  const float* w; u16* wT; int Ncols, Krows, bx, by;
  if (bid < 2816) { int l = bid - 2048; w = w_qkv; wT = wqkT; Ncols = 3072; Krows = 1024; bx = l % 48; by = l / 48; }
  else            { int l = bid - 2816; w = w_proj; wT = wpjT; Ncols = 1024; Krows = 1024; bx = l & 15; by = l >> 4; }
  int n0 = bx * 64, k0 = by * 64;
#pragma unroll
  for (int it = 0; it < 16; ++it) {
    int e = it * 256 + threadIdx.x;
    int r = e >> 6, c = e & 63;
    t[r][c] = f2bf(w[(size_t)(k0 + r) * Ncols + n0 + c]);
  }
  __syncthreads();
#pragma unroll
  for (int it = 0; it < 4; ++it) {
    int e = it * 256 + threadIdx.x;
    int r = e >> 4, c0 = (e & 15) * 4;   // r = local n, c0 = local k base
    union { u16 h[4]; uint2 v; } pk;
    pk.h[0] = t[c0][r]; pk.h[1] = t[c0 + 1][r];
    pk.h[2] = t[c0 + 2][r]; pk.h[3] = t[c0 + 3][r];
    *(uint2*)(wT + (size_t)(n0 + r) * Krows + k0 + c0) = pk.v;
  }
}

// ------- 128x128 bf16 MFMA GEMM, double-buffered LDS, ONE barrier per K-iter -------
// QKV epilogue: fused per-head RMSNorm on q/k (+ attention scale on q),
// scatter q/k -> [BH][N][D] bf16, V -> transposed [BH][D][N] f16.
__global__ __launch_bounds__(256, 3) void k_gemm_qkv(
    const u16* __restrict__ A, const u16* __restrict__ Bt,
    const float* __restrict__ bias,
    u16* __restrict__ oq, u16* __restrict__ ok, u16* __restrict__ ov,
    const float* __restrict__ qw, const float* __restrict__ kw,
    int K) {
  __shared__ u16 lA[2][128 * 32];
  __shared__ u16 lB[2][128 * 32];
  const int tid = threadIdx.x;
  const int lane = tid & 63, lrow = lane & 15, lq = lane >> 4;
  const int wave = tid >> 6;
  const int bm = blockIdx.y * 128, bn = blockIdx.x * 128;
  const int wm = (wave >> 1) * 64, wn = (wave & 1) * 64;

  const int ch0 = tid, ch1 = 256 + tid;
  const u16* ap0 = A + (size_t)(bm + (ch0 >> 2)) * K + (ch0 & 3) * 8;
  const u16* ap1 = A + (size_t)(bm + (ch1 >> 2)) * K + (ch1 & 3) * 8;
  const u16* bp0 = Bt + (size_t)(bn + (ch0 >> 2)) * K + (ch0 & 3) * 8;
  const u16* bp1 = Bt + (size_t)(bn + (ch1 >> 2)) * K + (ch1 & 3) * 8;

  uint4 pA0 = *(const uint4*)ap0, pA1 = *(const uint4*)ap1;
  uint4 pB0 = *(const uint4*)bp0, pB1 = *(const uint4*)bp1;

  f4 acc[4][4] = {};
  const int iters = K >> 5;
  for (int it = 0; it < iters; ++it) {
    const int s = it & 1;
    *(uint4*)(lA[s] + ch0 * 8) = pA0; *(uint4*)(lA[s] + ch1 * 8) = pA1;
    *(uint4*)(lB[s] + ch0 * 8) = pB0; *(uint4*)(lB[s] + ch1 * 8) = pB1;
    if (it + 1 < iters) {
      ap0 += 32; ap1 += 32; bp0 += 32; bp1 += 32;
      pA0 = *(const uint4*)ap0; pA1 = *(const uint4*)ap1;
      pB0 = *(const uint4*)bp0; pB1 = *(const uint4*)bp1;
    }
    __syncthreads();
    b8 af[4], bf[4];
#pragma unroll
    for (int i = 0; i < 4; ++i)
      af[i] = *(const b8*)(lA[s] + (wm + i * 16 + lrow) * 32 + lq * 8);
#pragma unroll
    for (int j = 0; j < 4; ++j)
      bf[j] = *(const b8*)(lB[s] + (wn + j * 16 + lrow) * 32 + lq * 8);
#pragma unroll
    for (int i = 0; i < 4; ++i)
#pragma unroll
      for (int j = 0; j < 4; ++j)
        acc[i][j] = __builtin_amdgcn_mfma_f32_16x16x32_bf16(af[i], bf[j], acc[i][j], 0, 0, 0);
  }

  float bv[4];
#pragma unroll
  for (int j = 0; j < 4; ++j) bv[j] = bias[bn + wn + j * 16 + lrow];

  const float CS = 0.125f * 1.44269504088896340736f;  // scale * log2(e), folded into q
  const int n0w = bn + wn;                 // 64-aligned: one head's D-range per wave
  const int sec = n0w >> 10;               // 0=q, 1=k, 2=v (wave-uniform)
  const int h = (n0w >> 6) & 15;
#pragma unroll
  for (int i = 0; i < 4; ++i) {
    float v[4][4];  // [j][r]
#pragma unroll
    for (int j = 0; j < 4; ++j)
#pragma unroll
      for (int r = 0; r < 4; ++r) v[j][r] = acc[i][j][r] + bv[j];
    if (sec < 2) {
      u16* dst = sec == 0 ? oq : ok;
      const float* w = sec == 0 ? qw : kw;
      float ex = sec == 0 ? CS : 1.0f;
#pragma unroll
      for (int r = 0; r < 4; ++r) {
        float ss = v[0][r] * v[0][r] + v[1][r] * v[1][r] +
                   v[2][r] * v[2][r] + v[3][r] * v[3][r];
        ss += __shfl_xor(ss, 1, 64); ss += __shfl_xor(ss, 2, 64);
        ss += __shfl_xor(ss, 4, 64); ss += __shfl_xor(ss, 8, 64);
        float sc = rsqrtf(ss * (1.0f / 64.0f) + 1e-6f) * ex;
        int m = bm + wm + i * 16 + lq * 4 + r;
        int bb = m >> 11, ns = m & 2047;
        u16* rowp = dst + ((size_t)(bb * 16 + h) * 2048 + ns) * 64;
#pragma unroll
        for (int j = 0; j < 4; ++j) {
          int d = j * 16 + lrow;
          rowp[d] = f2bf(v[j][r] * sc * w[d]);
        }
      }
    } else {
      int m0 = bm + wm + i * 16 + lq * 4;
      int bb = m0 >> 11, ns = m0 & 2047;
#pragma unroll
      for (int j = 0; j < 4; ++j) {
        int d = j * 16 + lrow;
        union { _Float16 hh[4]; uint2 u; } pk;
#pragma unroll
        for (int r = 0; r < 4; ++r) pk.hh[r] = (_Float16)v[j][r];
        *(uint2*)(ov + ((size_t)(bb * 16 + h) * 64 + d) * 2048 + ns) = pk.u;
      }
    }
  }
}

// ---- 128x128 bf16 MFMA GEMM for the out-proj (same structure as k_gemm_qkv).
// Grid 8x32 = 256 blocks = 1/CU. Plain bias + fp32 epilogue. ----
__global__ __launch_bounds__(256, 3) void k_gemm2(
    const u16* __restrict__ A, const u16* __restrict__ Bt,
    const float* __restrict__ bias, float* __restrict__ outF,
    int K, int Ncols) {
  __shared__ u16 lA[2][128 * 32];
  __shared__ u16 lB[2][128 * 32];
  const int tid = threadIdx.x;
  const int lane = tid & 63, lrow = lane & 15, lq = lane >> 4;
  const int wave = tid >> 6;
  const int bm = blockIdx.y * 128, bn = blockIdx.x * 128;
  const int wm = (wave >> 1) * 64, wn = (wave & 1) * 64;

  const int ch0 = tid, ch1 = 256 + tid;
  const u16* ap0 = A + (size_t)(bm + (ch0 >> 2)) * K + (ch0 & 3) * 8;
  const u16* ap1 = A + (size_t)(bm + (ch1 >> 2)) * K + (ch1 & 3) * 8;
  const u16* bp0 = Bt + (size_t)(bn + (ch0 >> 2)) * K + (ch0 & 3) * 8;
  const u16* bp1 = Bt + (size_t)(bn + (ch1 >> 2)) * K + (ch1 & 3) * 8;

  uint4 pA0 = *(const uint4*)ap0, pA1 = *(const uint4*)ap1;
  uint4 pB0 = *(const uint4*)bp0, pB1 = *(const uint4*)bp1;

  f4 acc[4][4] = {};
  const int iters = K >> 5;
  for (int it = 0; it < iters; ++it) {
    const int s = it & 1;
    *(uint4*)(lA[s] + ch0 * 8) = pA0; *(uint4*)(lA[s] + ch1 * 8) = pA1;
    *(uint4*)(lB[s] + ch0 * 8) = pB0; *(uint4*)(lB[s] + ch1 * 8) = pB1;
    if (it + 1 < iters) {
      ap0 += 32; ap1 += 32; bp0 += 32; bp1 += 32;
      pA0 = *(const uint4*)ap0; pA1 = *(const uint4*)ap1;
      pB0 = *(const uint4*)bp0; pB1 = *(const uint4*)bp1;
    }
    __syncthreads();
    b8 af[4], bf[4];
#pragma unroll
    for (int i = 0; i < 4; ++i)
      af[i] = *(const b8*)(lA[s] + (wm + i * 16 + lrow) * 32 + lq * 8);
#pragma unroll
    for (int j = 0; j < 4; ++j)
      bf[j] = *(const b8*)(lB[s] + (wn + j * 16 + lrow) * 32 + lq * 8);
#pragma unroll
    for (int i = 0; i < 4; ++i)
#pragma unroll
      for (int j = 0; j < 4; ++j)
        acc[i][j] = __builtin_amdgcn_mfma_f32_16x16x32_bf16(af[i], bf[j], acc[i][j], 0, 0, 0);
  }
#pragma unroll
  for (int j = 0; j < 4; ++j) {
    int n = bn + wn + j * 16 + lrow;
    float bv = bias[n];
#pragma unroll
    for (int i = 0; i < 4; ++i)
#pragma unroll
      for (int r = 0; r < 4; ++r) {
        int m = bm + wm + i * 16 + lq * 4 + r;
        outF[(size_t)m * Ncols + n] = acc[i][j][r] + bv;
      }
  }
}

// -------- flash attention, S^T orientation, QUAD-q (64 q/wave) --------
// R21 theory: LDS data-path is the binding pipe. K/V fragment reads are
// wave-independent (only Q/P B-operands differ per wave), so per-CU LDS
// read traffic scales as 1/(q per wave). R19 (16 q/wave) saturated LDS
// (8.2k cyc demand vs 7.9k wall per 256q-iter); R18 (32 q/wave) = 4.1k.
// This: 64 q/wave, 4 waves x 64q = 256 q/block, grid 256 = 1 block/CU.
// LDS ~2.3k cyc/iter, matrix pipe ~2.5k/iter becomes the limiter.
// Key-quarter split (c=0..3: QK 2 kt-tiles -> exp -> PV kp=c) keeps st
// live-range at 32 VGPRs (vs 128 for full-width) and gives the single
// wave/SIMD interleavable MFMA/VALU/LDS chains across quarters.
// launch_bounds(256,1): 1 wave/SIMD may use up to 512 VGPR, no spill risk.
// Keeps: PV K=32 zero-shuffle repack, XCD swizzle (bh = b&31: same-bh
// blocks land on one XCD; K+V 512KB/bh L2-resident), no-max softmax
// (|st|<=11.6, p=exp2(st)), VALU lsum, dbuf ONE barrier per K-iter,
// proven LDS strides (K:72, V:140) and fragment mappings.
__global__ __launch_bounds__(256, 1) void k_attn(
    const u16* __restrict__ qb, const u16* __restrict__ kb,
    const u16* __restrict__ vt, u16* __restrict__ ao) {
  __shared__ u16 lK[2][128 * 72];   // [key][d] bf16, stride 72 (9x16B)
  __shared__ u16 lV[2][64 * 140];   // [d][key] f16, stride 140 (35 8B-granules, odd)
  const int b = blockIdx.x;
  const int bh = b & 31;          // XCD swizzle: same-bh blocks == same id mod 8
  const int q0 = (b >> 5) * 256;
  const int tid = threadIdx.x, wave = tid >> 6, lane = tid & 63;
  const int lrow = lane & 15, lq = lane >> 4;
  const int wq = wave * 64;

  // Q fragments, four 16-q groups (B-operand: n=q=lane&15, k=d=quad*8+j); CS pre-folded
  b8 qf[4][2];
#pragma unroll
  for (int g = 0; g < 4; ++g)
#pragma unroll
    for (int ks = 0; ks < 2; ++ks)
      qf[g][ks] = *(const b8*)(qb + ((size_t)bh * 2048 + q0 + wq + g * 16 + lrow) * 64 +
                               ks * 32 + lq * 8);

  f4 o[4][4] = {};     // O^T partials [g][dt]: row=d=quad*4+r, col=q=lane&15
  f4 lsum[4] = {};     // deferred l partials (VALU; reduced once at the end)

  // staging: K tile 128x64 = 1024 chunks + V tile 64x128 = 1024; 8/thread
  const u16* kbase = kb + (size_t)bh * 2048 * 64;
  const u16* vbase = vt + (size_t)bh * 64 * 2048;
  const u16* kp[4]; const u16* vp[4];
  int kO[4], vO[4];
#pragma unroll
  for (int i = 0; i < 4; ++i) {
    int ch = tid + 256 * i;
    kp[i] = kbase + (size_t)(ch >> 3) * 64 + (ch & 7) * 8;
    kO[i] = (ch >> 3) * 72 + (ch & 7) * 8;
    vp[i] = vbase + (size_t)(ch >> 4) * 2048 + (ch & 15) * 8;
    vO[i] = (ch >> 4) * 140 + (ch & 15) * 8;
  }
  uint4 pK[4], pV[4];
#pragma unroll
  for (int i = 0; i < 4; ++i) { pK[i] = *(const uint4*)kp[i]; pV[i] = *(const uint4*)vp[i]; }

  for (int it = 0; it < 16; ++it) {
    const int s = it & 1;
    // store prefetched tile regs -> LDS buf[s]
#pragma unroll
    for (int i = 0; i < 4; ++i) {
      *(uint4*)(lK[s] + kO[i]) = pK[i];
      *(uint2*)(lV[s] + vO[i]) = make_uint2(pV[i].x, pV[i].y);   // 280B rows: 8B-aligned only
      *(uint2*)(lV[s] + vO[i] + 4) = make_uint2(pV[i].z, pV[i].w);
    }
    // issue next tile's global loads; they drain during the compute below
    if (it < 15) {
#pragma unroll
      for (int i = 0; i < 4; ++i) {
        kp[i] += 128 * 64; vp[i] += 128;
        pK[i] = *(const uint4*)kp[i]; pV[i] = *(const uint4*)vp[i];
      }
    }
    __syncthreads();   // single barrier: buf[s] visible; buf[s^1] free for next store

    // 4 key-quarters: {QK over 2 kt-tiles} -> {exp2 + pack} -> {PV kp=c}
#pragma unroll
    for (int c = 0; c < 4; ++c) {
      f4 st[4][2] = {};
#pragma unroll
      for (int ks = 0; ks < 2; ++ks)
#pragma unroll
        for (int t = 0; t < 2; ++t) {
          b8 kf = *(const b8*)(lK[s] + ((c * 2 + t) * 16 + lrow) * 72 + ks * 32 + lq * 8);
#pragma unroll
          for (int g = 0; g < 4; ++g)
            st[g][t] = __builtin_amdgcn_mfma_f32_16x16x32_bf16(kf, qf[g][ks], st[g][t], 0, 0, 0);
        }

      // p = exp2(st); pack tile pair {2c,2c+1} into lane-local K=32 f16
      // B-fragments (B slot lq*8+j := key (j<4?2c:2c+1)*16 + lq*4 + (j&3))
      h8 pf[4];
#pragma unroll
      for (int g = 0; g < 4; ++g) {
        f4 eA, eB;
#pragma unroll
        for (int r = 0; r < 4; ++r) eA[r] = EXP2(st[g][0][r]);
#pragma unroll
        for (int r = 0; r < 4; ++r) eB[r] = EXP2(st[g][1][r]);
        lsum[g] += eA;
        lsum[g] += eB;
        union { hp2 p2[4]; h8 v; } cv;
        cv.p2[0] = __builtin_amdgcn_cvt_pkrtz(eA[0], eA[1]);
        cv.p2[1] = __builtin_amdgcn_cvt_pkrtz(eA[2], eA[3]);
        cv.p2[2] = __builtin_amdgcn_cvt_pkrtz(eB[0], eB[1]);
        cv.p2[3] = __builtin_amdgcn_cvt_pkrtz(eB[2], eB[3]);
        pf[g] = cv.v;
      }

      // O^T += V^T·P^T — va = two 4-key b64 runs 16 apart; each read feeds 4 MFMAs
#pragma unroll
      for (int dt = 0; dt < 4; ++dt) {
        const u16* vb = lV[s] + (dt * 16 + lrow) * 140 + c * 32 + lq * 4;
        union { h4 q[2]; h8 v; } va;
        va.q[0] = *(const h4*)vb;
        va.q[1] = *(const h4*)(vb + 16);
#pragma unroll
        for (int g = 0; g < 4; ++g)
          o[g][dt] = __builtin_amdgcn_mfma_f32_16x16x32_f16(va.v, pf[g], o[g][dt], 0, 0, 0);
      }
    }
  }

  const int bb = bh >> 4, h = bh & 15;
#pragma unroll
  for (int g = 0; g < 4; ++g) {
    // final l reduction: 4 regs + 2 shuffles across the 4 quads
    float l = lsum[g][0] + lsum[g][1] + lsum[g][2] + lsum[g][3];
    l += __shfl_xor(l, 16, 64);
    l += __shfl_xor(l, 32, 64);
    float inv = 1.0f / l;
    int q = q0 + wq + g * 16 + lrow;
#pragma unroll
    for (int dt = 0; dt < 4; ++dt) {
      union { u16 h2[4]; uint2 v; } r;
#pragma unroll
      for (int rr = 0; rr < 4; ++rr) r.h2[rr] = f2bf(o[g][dt][rr] * inv);
      *(uint2*)(ao + ((size_t)bb * 2048 + q) * 1024 + h * 64 + dt * 16 + lq * 4) = r.v;
    }
  }
}

extern "C" void kernel_launch(void* const* d_in, const int* in_sizes, int n_in,
                              void* d_out, int out_size, void* d_ws, size_t ws_size,
                              hipStream_t stream) {
  const float* x      = (const float*)d_in[0];
  const float* w_qkv  = (const float*)d_in[1];
  const float* b_qkv  = (const float*)d_in[2];
  const float* q_w    = (const float*)d_in[3];
  const float* k_w    = (const float*)d_in[4];
  const float* w_proj = (const float*)d_in[5];
  const float* b_proj = (const float*)d_in[6];
  float* out = (float*)d_out;

  u16* xb   = (u16*)d_ws;          // 4096x1024 bf16
  u16* wqkT = xb + 4194304;        // 3072x1024 bf16
  u16* wpjT = wqkT + 3145728;      // 1024x1024 bf16
  u16* qb   = wpjT + 1048576;      // [BH][N][D] bf16 (CS-scaled)
  u16* kb   = qb + 4194304;        // [BH][N][D] bf16
  u16* vtb  = kb + 4194304;        // [BH][D][N] f16
  u16* ao   = xb;                  // attention out reuses xb

  k_convert_all<<<3072, 256, 0, stream>>>(x, w_qkv, w_proj, xb, wqkT, wpjT);
  k_gemm_qkv<<<dim3(24, 32), 256, 0, stream>>>(xb, wqkT, b_qkv, qb, kb, vtb, q_w, k_w, 1024);
  k_attn<<<256, 256, 0, stream>>>(qb, kb, vtb, ao);
  k_gemm2<<<dim3(8, 32), 256, 0, stream>>>(ao, wpjT, b_proj, out, 1024, 1024);
}

// Round 5
// 180.211 us; speedup vs baseline: 1.1639x; 1.1639x over previous
//
#include <hip/hip_runtime.h>

typedef unsigned short u16;
typedef unsigned int u32;
typedef float f4 __attribute__((ext_vector_type(4)));
typedef __bf16 b8 __attribute__((ext_vector_type(8)));
typedef _Float16 h4 __attribute__((ext_vector_type(4)));
typedef _Float16 h8 __attribute__((ext_vector_type(8)));
typedef __fp16 hp2 __attribute__((ext_vector_type(2)));

#if __has_builtin(__builtin_amdgcn_exp2f)
#define EXP2(x) __builtin_amdgcn_exp2f(x)
#else
#define EXP2(x) exp2f(x)
#endif

__device__ __forceinline__ u16 f2bf(float f) {
  unsigned u = __float_as_uint(f);
  u += 0x7fffu + ((u >> 16) & 1u);
  return (u16)(u >> 16);
}
__device__ __forceinline__ float bf2f(u16 h) {
  return __uint_as_float(((unsigned)h) << 16);
}

// ------- fused input conversion: x fp32->bf16 + both weights fp32->bf16 transposed -------
__global__ void k_convert_all(const float* __restrict__ x,
                              const float* __restrict__ w_qkv,
                              const float* __restrict__ w_proj,
                              u16* __restrict__ xb, u16* __restrict__ wqkT,
                              u16* __restrict__ wpjT) {
  __shared__ u16 t[64][65];
  int bid = blockIdx.x;
  if (bid < 2048) {  // x convert, same layout
    int i = (bid * 256 + threadIdx.x) * 8;
    float4 a = *(const float4*)(x + i);
    float4 b = *(const float4*)(x + i + 4);
    union { u16 h[8]; uint4 v; } r;
    r.h[0] = f2bf(a.x); r.h[1] = f2bf(a.y); r.h[2] = f2bf(a.z); r.h[3] = f2bf(a.w);
    r.h[4] = f2bf(b.x); r.h[5] = f2bf(b.y); r.h[6] = f2bf(b.z); r.h[7] = f2bf(b.w);
    *(uint4*)(xb + i) = r.v;
    return;
  }
  const float* w; u16* wT; int Ncols, Krows, bx, by;
  if (bid < 2816) { int l = bid - 2048; w = w_qkv; wT = wqkT; Ncols = 3072; Krows = 1024; bx = l % 48; by = l / 48; }
  else            { int l = bid - 2816; w = w_proj; wT = wpjT; Ncols = 1024; Krows = 1024; bx = l & 15; by = l >> 4; }
  int n0 = bx * 64, k0 = by * 64;
#pragma unroll
  for (int it = 0; it < 16; ++it) {
    int e = it * 256 + threadIdx.x;
    int r = e >> 6, c = e & 63;
    t[r][c] = f2bf(w[(size_t)(k0 + r) * Ncols + n0 + c]);
  }
  __syncthreads();
#pragma unroll
  for (int it = 0; it < 4; ++it) {
    int e = it * 256 + threadIdx.x;
    int r = e >> 4, c0 = (e & 15) * 4;   // r = local n, c0 = local k base
    union { u16 h[4]; uint2 v; } pk;
    pk.h[0] = t[c0][r]; pk.h[1] = t[c0 + 1][r];
    pk.h[2] = t[c0 + 2][r]; pk.h[3] = t[c0 + 3][r];
    *(uint2*)(wT + (size_t)(n0 + r) * Krows + k0 + c0) = pk.v;
  }
}

// ------- 128x128 bf16 MFMA GEMM, double-buffered LDS, ONE barrier per K-iter -------
// QKV epilogue: fused per-head RMSNorm on q/k (+ attention scale on q),
// scatter q/k -> [BH][N][D] bf16, V -> transposed [BH][D][N] f16.
__global__ __launch_bounds__(256, 3) void k_gemm_qkv(
    const u16* __restrict__ A, const u16* __restrict__ Bt,
    const float* __restrict__ bias,
    u16* __restrict__ oq, u16* __restrict__ ok, u16* __restrict__ ov,
    const float* __restrict__ qw, const float* __restrict__ kw,
    int K) {
  __shared__ u16 lA[2][128 * 32];
  __shared__ u16 lB[2][128 * 32];
  const int tid = threadIdx.x;
  const int lane = tid & 63, lrow = lane & 15, lq = lane >> 4;
  const int wave = tid >> 6;
  const int bm = blockIdx.y * 128, bn = blockIdx.x * 128;
  const int wm = (wave >> 1) * 64, wn = (wave & 1) * 64;

  const int ch0 = tid, ch1 = 256 + tid;
  const u16* ap0 = A + (size_t)(bm + (ch0 >> 2)) * K + (ch0 & 3) * 8;
  const u16* ap1 = A + (size_t)(bm + (ch1 >> 2)) * K + (ch1 & 3) * 8;
  const u16* bp0 = Bt + (size_t)(bn + (ch0 >> 2)) * K + (ch0 & 3) * 8;
  const u16* bp1 = Bt + (size_t)(bn + (ch1 >> 2)) * K + (ch1 & 3) * 8;

  uint4 pA0 = *(const uint4*)ap0, pA1 = *(const uint4*)ap1;
  uint4 pB0 = *(const uint4*)bp0, pB1 = *(const uint4*)bp1;

  f4 acc[4][4] = {};
  const int iters = K >> 5;
  for (int it = 0; it < iters; ++it) {
    const int s = it & 1;
    *(uint4*)(lA[s] + ch0 * 8) = pA0; *(uint4*)(lA[s] + ch1 * 8) = pA1;
    *(uint4*)(lB[s] + ch0 * 8) = pB0; *(uint4*)(lB[s] + ch1 * 8) = pB1;
    if (it + 1 < iters) {
      ap0 += 32; ap1 += 32; bp0 += 32; bp1 += 32;
      pA0 = *(const uint4*)ap0; pA1 = *(const uint4*)ap1;
      pB0 = *(const uint4*)bp0; pB1 = *(const uint4*)bp1;
    }
    __syncthreads();
    b8 af[4], bf[4];
#pragma unroll
    for (int i = 0; i < 4; ++i)
      af[i] = *(const b8*)(lA[s] + (wm + i * 16 + lrow) * 32 + lq * 8);
#pragma unroll
    for (int j = 0; j < 4; ++j)
      bf[j] = *(const b8*)(lB[s] + (wn + j * 16 + lrow) * 32 + lq * 8);
#pragma unroll
    for (int i = 0; i < 4; ++i)
#pragma unroll
      for (int j = 0; j < 4; ++j)
        acc[i][j] = __builtin_amdgcn_mfma_f32_16x16x32_bf16(af[i], bf[j], acc[i][j], 0, 0, 0);
  }

  float bv[4];
#pragma unroll
  for (int j = 0; j < 4; ++j) bv[j] = bias[bn + wn + j * 16 + lrow];

  const float CS = 0.125f * 1.44269504088896340736f;  // scale * log2(e), folded into q
  const int n0w = bn + wn;                 // 64-aligned: one head's D-range per wave
  const int sec = n0w >> 10;               // 0=q, 1=k, 2=v (wave-uniform)
  const int h = (n0w >> 6) & 15;
#pragma unroll
  for (int i = 0; i < 4; ++i) {
    float v[4][4];  // [j][r]
#pragma unroll
    for (int j = 0; j < 4; ++j)
#pragma unroll
      for (int r = 0; r < 4; ++r) v[j][r] = acc[i][j][r] + bv[j];
    if (sec < 2) {
      u16* dst = sec == 0 ? oq : ok;
      const float* w = sec == 0 ? qw : kw;
      float ex = sec == 0 ? CS : 1.0f;
#pragma unroll
      for (int r = 0; r < 4; ++r) {
        float ss = v[0][r] * v[0][r] + v[1][r] * v[1][r] +
                   v[2][r] * v[2][r] + v[3][r] * v[3][r];
        ss += __shfl_xor(ss, 1, 64); ss += __shfl_xor(ss, 2, 64);
        ss += __shfl_xor(ss, 4, 64); ss += __shfl_xor(ss, 8, 64);
        float sc = rsqrtf(ss * (1.0f / 64.0f) + 1e-6f) * ex;
        int m = bm + wm + i * 16 + lq * 4 + r;
        int bb = m >> 11, ns = m & 2047;
        u16* rowp = dst + ((size_t)(bb * 16 + h) * 2048 + ns) * 64;
#pragma unroll
        for (int j = 0; j < 4; ++j) {
          int d = j * 16 + lrow;
          rowp[d] = f2bf(v[j][r] * sc * w[d]);
        }
      }
    } else {
      int m0 = bm + wm + i * 16 + lq * 4;
      int bb = m0 >> 11, ns = m0 & 2047;
#pragma unroll
      for (int j = 0; j < 4; ++j) {
        int d = j * 16 + lrow;
        union { _Float16 hh[4]; uint2 u; } pk;
#pragma unroll
        for (int r = 0; r < 4; ++r) pk.hh[r] = (_Float16)v[j][r];
        *(uint2*)(ov + ((size_t)(bb * 16 + h) * 64 + d) * 2048 + ns) = pk.u;
      }
    }
  }
}

// ---- 128x128 bf16 MFMA GEMM for the out-proj (same structure as k_gemm_qkv).
// Grid 8x32 = 256 blocks = 1/CU. Plain bias + fp32 epilogue. ----
__global__ __launch_bounds__(256, 3) void k_gemm2(
    const u16* __restrict__ A, const u16* __restrict__ Bt,
    const float* __restrict__ bias, float* __restrict__ outF,
    int K, int Ncols) {
  __shared__ u16 lA[2][128 * 32];
  __shared__ u16 lB[2][128 * 32];
  const int tid = threadIdx.x;
  const int lane = tid & 63, lrow = lane & 15, lq = lane >> 4;
  const int wave = tid >> 6;
  const int bm = blockIdx.y * 128, bn = blockIdx.x * 128;
  const int wm = (wave >> 1) * 64, wn = (wave & 1) * 64;

  const int ch0 = tid, ch1 = 256 + tid;
  const u16* ap0 = A + (size_t)(bm + (ch0 >> 2)) * K + (ch0 & 3) * 8;
  const u16* ap1 = A + (size_t)(bm + (ch1 >> 2)) * K + (ch1 & 3) * 8;
  const u16* bp0 = Bt + (size_t)(bn + (ch0 >> 2)) * K + (ch0 & 3) * 8;
  const u16* bp1 = Bt + (size_t)(bn + (ch1 >> 2)) * K + (ch1 & 3) * 8;

  uint4 pA0 = *(const uint4*)ap0, pA1 = *(const uint4*)ap1;
  uint4 pB0 = *(const uint4*)bp0, pB1 = *(const uint4*)bp1;

  f4 acc[4][4] = {};
  const int iters = K >> 5;
  for (int it = 0; it < iters; ++it) {
    const int s = it & 1;
    *(uint4*)(lA[s] + ch0 * 8) = pA0; *(uint4*)(lA[s] + ch1 * 8) = pA1;
    *(uint4*)(lB[s] + ch0 * 8) = pB0; *(uint4*)(lB[s] + ch1 * 8) = pB1;
    if (it + 1 < iters) {
      ap0 += 32; ap1 += 32; bp0 += 32; bp1 += 32;
      pA0 = *(const uint4*)ap0; pA1 = *(const uint4*)ap1;
      pB0 = *(const uint4*)bp0; pB1 = *(const uint4*)bp1;
    }
    __syncthreads();
    b8 af[4], bf[4];
#pragma unroll
    for (int i = 0; i < 4; ++i)
      af[i] = *(const b8*)(lA[s] + (wm + i * 16 + lrow) * 32 + lq * 8);
#pragma unroll
    for (int j = 0; j < 4; ++j)
      bf[j] = *(const b8*)(lB[s] + (wn + j * 16 + lrow) * 32 + lq * 8);
#pragma unroll
    for (int i = 0; i < 4; ++i)
#pragma unroll
      for (int j = 0; j < 4; ++j)
        acc[i][j] = __builtin_amdgcn_mfma_f32_16x16x32_bf16(af[i], bf[j], acc[i][j], 0, 0, 0);
  }
#pragma unroll
  for (int j = 0; j < 4; ++j) {
    int n = bn + wn + j * 16 + lrow;
    float bv = bias[n];
#pragma unroll
    for (int i = 0; i < 4; ++i)
#pragma unroll
      for (int r = 0; r < 4; ++r) {
        int m = bm + wm + i * 16 + lq * 4 + r;
        outF[(size_t)m * Ncols + n] = acc[i][j][r] + bv;
      }
  }
}

// -------- flash attention, S^T orientation, dual-q + KEY-QUARTER INTERLEAVE --------
// R22. Triangulated from R18/R19/R21: (a) q/wave amortization sets LDS read
// traffic (R19: 16q/wave saturated LDS); (b) >=2 waves/SIMD needed to cover
// dependency latencies (R21: 1/SIMD, MfmaUtil 17%); (c) R18's monolithic
// phases (32 QK MFMA -> 64 exp -> 32 PV MFMA) make all co-resident waves mob
// one pipe at a time (busy-sum ~6000 < wall 7275). This: R18 geometry
// (8 waves x 32q dual-q, grid 256, 2 waves/SIMD) + R21's key-quarter loop:
// 4x {QK 2 kt-tiles -> exp2+pack -> PV} per K-iter. st live range 128->32
// regs; 4 independent chains/iter let the compiler interleave quarter c+1's
// QK with quarter c's exp/PV, and the 2 waves/SIMD destagger across pipes.
// Keeps: PV K=32 zero-shuffle repack, XCD swizzle (bh = b&31), no-max
// softmax (|st|<=11.6, p=exp2(st)), VALU lsum, dbuf ONE barrier per K-iter,
// proven LDS strides (K:72, V:140), setprio(1) around MFMA clusters.
__global__ __launch_bounds__(512, 2) void k_attn(
    const u16* __restrict__ qb, const u16* __restrict__ kb,
    const u16* __restrict__ vt, u16* __restrict__ ao) {
  __shared__ u16 lK[2][128 * 72];   // [key][d] bf16, stride 72 (9x16B)
  __shared__ u16 lV[2][64 * 140];   // [d][key] f16, stride 140 (35 8B-granules, odd)
  const int b = blockIdx.x;
  const int bh = b & 31;          // XCD swizzle: same-bh blocks == same id mod 8
  const int q0 = (b >> 5) * 256;
  const int tid = threadIdx.x, wave = tid >> 6, lane = tid & 63;
  const int lrow = lane & 15, lq = lane >> 4;
  const int wq = wave * 32;

  // Q fragments, two 16-q groups (B-operand: n=q=lane&15, k=d=quad*8+j); CS pre-folded
  b8 qf[2][2];
#pragma unroll
  for (int g = 0; g < 2; ++g)
#pragma unroll
    for (int ks = 0; ks < 2; ++ks)
      qf[g][ks] = *(const b8*)(qb + ((size_t)bh * 2048 + q0 + wq + g * 16 + lrow) * 64 +
                               ks * 32 + lq * 8);

  f4 o[2][4] = {};     // O^T partials [g][dt]: row=d=quad*4+r, col=q=lane&15
  f4 lsum[2] = {};     // deferred l partials (VALU; reduced once at the end)

  // staging: K tile 128x64 = 1024 chunks + V tile 64x128 = 1024; 4/thread
  const int ch0 = tid, ch1 = 512 + tid;
  const u16* kp0 = kb + (size_t)bh * 2048 * 64 + (size_t)(ch0 >> 3) * 64 + (ch0 & 7) * 8;
  const u16* kp1 = kb + (size_t)bh * 2048 * 64 + (size_t)(ch1 >> 3) * 64 + (ch1 & 7) * 8;
  const u16* vp0 = vt + (size_t)bh * 64 * 2048 + (size_t)(ch0 >> 4) * 2048 + (ch0 & 15) * 8;
  const u16* vp1 = vt + (size_t)bh * 64 * 2048 + (size_t)(ch1 >> 4) * 2048 + (ch1 & 15) * 8;
  const int kO0 = (ch0 >> 3) * 72 + (ch0 & 7) * 8;
  const int kO1 = (ch1 >> 3) * 72 + (ch1 & 7) * 8;
  const int vO0 = (ch0 >> 4) * 140 + (ch0 & 15) * 8;
  const int vO1 = (ch1 >> 4) * 140 + (ch1 & 15) * 8;

  uint4 pK0 = *(const uint4*)kp0, pK1 = *(const uint4*)kp1;
  uint4 pV0 = *(const uint4*)vp0, pV1 = *(const uint4*)vp1;

  for (int it = 0; it < 16; ++it) {
    const int s = it & 1;
    // store prefetched tile regs -> LDS buf[s]
    *(uint4*)(lK[s] + kO0) = pK0;
    *(uint4*)(lK[s] + kO1) = pK1;
    *(uint2*)(lV[s] + vO0) = make_uint2(pV0.x, pV0.y);     // 280B rows not 16B-aligned
    *(uint2*)(lV[s] + vO0 + 4) = make_uint2(pV0.z, pV0.w);
    *(uint2*)(lV[s] + vO1) = make_uint2(pV1.x, pV1.y);
    *(uint2*)(lV[s] + vO1 + 4) = make_uint2(pV1.z, pV1.w);

    // issue next tile's global loads; they drain during the compute below
    if (it < 15) {
      kp0 += 128 * 64; kp1 += 128 * 64; vp0 += 128; vp1 += 128;
      pK0 = *(const uint4*)kp0; pK1 = *(const uint4*)kp1;
      pV0 = *(const uint4*)vp0; pV1 = *(const uint4*)vp1;
    }
    __syncthreads();   // single barrier: buf[s] visible; buf[s^1] free for next store

    // 4 key-quarters: {QK over 2 kt-tiles} -> {exp2 + pack} -> {PV kp=c}
#pragma unroll
    for (int c = 0; c < 4; ++c) {
      f4 st[2][2] = {};
      __builtin_amdgcn_s_setprio(1);
#pragma unroll
      for (int ks = 0; ks < 2; ++ks)
#pragma unroll
        for (int t = 0; t < 2; ++t) {
          b8 kf = *(const b8*)(lK[s] + ((c * 2 + t) * 16 + lrow) * 72 + ks * 32 + lq * 8);
          st[0][t] = __builtin_amdgcn_mfma_f32_16x16x32_bf16(kf, qf[0][ks], st[0][t], 0, 0, 0);
          st[1][t] = __builtin_amdgcn_mfma_f32_16x16x32_bf16(kf, qf[1][ks], st[1][t], 0, 0, 0);
        }
      __builtin_amdgcn_s_setprio(0);

      // p = exp2(st); pack tile pair {2c,2c+1} into lane-local K=32 f16
      // B-fragments (B slot lq*8+j := key (j<4?2c:2c+1)*16 + lq*4 + (j&3))
      h8 pf[2];
#pragma unroll
      for (int g = 0; g < 2; ++g) {
        f4 eA, eB;
#pragma unroll
        for (int r = 0; r < 4; ++r) eA[r] = EXP2(st[g][0][r]);
#pragma unroll
        for (int r = 0; r < 4; ++r) eB[r] = EXP2(st[g][1][r]);
        lsum[g] += eA;
        lsum[g] += eB;
        union { hp2 p2[4]; h8 v; } cv;
        cv.p2[0] = __builtin_amdgcn_cvt_pkrtz(eA[0], eA[1]);
        cv.p2[1] = __builtin_amdgcn_cvt_pkrtz(eA[2], eA[3]);
        cv.p2[2] = __builtin_amdgcn_cvt_pkrtz(eB[0], eB[1]);
        cv.p2[3] = __builtin_amdgcn_cvt_pkrtz(eB[2], eB[3]);
        pf[g] = cv.v;
      }

      // O^T += V^T·P^T — va = two 4-key b64 runs 16 apart; each feeds 2 MFMAs
      __builtin_amdgcn_s_setprio(1);
#pragma unroll
      for (int dt = 0; dt < 4; ++dt) {
        const u16* vb = lV[s] + (dt * 16 + lrow) * 140 + c * 32 + lq * 4;
        union { h4 q[2]; h8 v; } va;
        va.q[0] = *(const h4*)vb;
        va.q[1] = *(const h4*)(vb + 16);
        o[0][dt] = __builtin_amdgcn_mfma_f32_16x16x32_f16(va.v, pf[0], o[0][dt], 0, 0, 0);
        o[1][dt] = __builtin_amdgcn_mfma_f32_16x16x32_f16(va.v, pf[1], o[1][dt], 0, 0, 0);
      }
      __builtin_amdgcn_s_setprio(0);
    }
  }

  const int bb = bh >> 4, h = bh & 15;
#pragma unroll
  for (int g = 0; g < 2; ++g) {
    // final l reduction: 4 regs + 2 shuffles across the 4 quads
    float l = lsum[g][0] + lsum[g][1] + lsum[g][2] + lsum[g][3];
    l += __shfl_xor(l, 16, 64);
    l += __shfl_xor(l, 32, 64);
    float inv = 1.0f / l;
    int q = q0 + wq + g * 16 + lrow;
#pragma unroll
    for (int dt = 0; dt < 4; ++dt) {
      union { u16 h2[4]; uint2 v; } r;
#pragma unroll
      for (int rr = 0; rr < 4; ++rr) r.h2[rr] = f2bf(o[g][dt][rr] * inv);
      *(uint2*)(ao + ((size_t)bb * 2048 + q) * 1024 + h * 64 + dt * 16 + lq * 4) = r.v;
    }
  }
}

extern "C" void kernel_launch(void* const* d_in, const int* in_sizes, int n_in,
                              void* d_out, int out_size, void* d_ws, size_t ws_size,
                              hipStream_t stream) {
  const float* x      = (const float*)d_in[0];
  const float* w_qkv  = (const float*)d_in[1];
  const float* b_qkv  = (const float*)d_in[2];
  const float* q_w    = (const float*)d_in[3];
  const float* k_w    = (const float*)d_in[4];
  const float* w_proj = (const float*)d_in[5];
  const float* b_proj = (const float*)d_in[6];
  float* out = (float*)d_out;

  u16* xb   = (u16*)d_ws;          // 4096x1024 bf16
  u16* wqkT = xb + 4194304;        // 3072x1024 bf16
  u16* wpjT = wqkT + 3145728;      // 1024x1024 bf16
  u16* qb   = wpjT + 1048576;      // [BH][N][D] bf16 (CS-scaled)
  u16* kb   = qb + 4194304;        // [BH][N][D] bf16
  u16* vtb  = kb + 4194304;        // [BH][D][N] f16
  u16* ao   = xb;                  // attention out reuses xb

  k_convert_all<<<3072, 256, 0, stream>>>(x, w_qkv, w_proj, xb, wqkT, wpjT);
  k_gemm_qkv<<<dim3(24, 32), 256, 0, stream>>>(xb, wqkT, b_qkv, qb, kb, vtb, q_w, k_w, 1024);
  k_attn<<<256, 512, 0, stream>>>(qb, kb, vtb, ao);
  k_gemm2<<<dim3(8, 32), 256, 0, stream>>>(ao, wpjT, b_proj, out, 1024, 1024);
}